// Round 13
// baseline (88.472 us; speedup 1.0000x reference)
//
#include <hip/hip_runtime.h>

// Problem constants: input [8,16,512,1024] f32, disp [8,1,512,1024] f32
constexpr int B = 8;
constexpr int C = 16;
constexpr int H = 512;
constexpr int W = 1024;
constexpr int HW = H * W;
constexpr int CPB = 8;               // channels per block (R8 geometry)
constexpr int THREADS = 512;         // 8 waves
constexpr int NBLK = B * H * 2;      // 8192 one-shot blocks

typedef float f32x4 __attribute__((ext_vector_type(4)));
typedef float f32x2 __attribute__((ext_vector_type(2)));

// R8 (best: 85.4 us) with ONE change: thread t owns positions 2t, 2t+1 ->
// disp load and output store are dwordx2 (512 B per wave-instr, 2x fewer
// store instructions, chunkier HBM write bursts). Gather base ~ 2*lane+d ->
// 2 lanes/bank = free (m136); float4 width would be 32-way-conflicted, so
// x2 is the widest safe store without an LDS swizzle.
//   x  = clip(w + disp, 0, W-1); x0 = floor(x); x1 = min(x0+1, W-1)
//   wl = x1 - x; wr = x - x0   (both exactly 0 when x0 == W-1, so reading
//   from a = min(x0, W-2) and a+1 is always correct AND always in-bounds)
__global__ __launch_bounds__(THREADS) void warp_lds_x2(
    const float* __restrict__ input,
    const float* __restrict__ disp,
    float* __restrict__ out)
{
    __shared__ float lds[CPB * W];      // 32 KiB -> 4 blocks/CU

    const int g  = blockIdx.x;
    const int bh = g >> 1;              // b*H + h
    const int cg = g & 1;               // channel group (0: c0-7, 1: c8-15)
    const int b  = bh >> 9;             // H = 512
    const int h  = bh & (H - 1);
    const int t  = threadIdx.x;

    const int base0 = ((b * C) + cg * CPB) * HW + h * W;   // (b, cg*8, h, 0)

    // ---- Stage: 8 rows x 1024 floats = 2048 float4; 4 per thread ----
#pragma unroll
    for (int i = 0; i < 4; ++i) {
        const int f = t + i * THREADS;      // float4 index in [0, 2048)
        const int c = f >> 8;               // 256 float4 per channel row
        const int q = (f & 255) << 2;       // float offset within row
        const f32x4 v = *reinterpret_cast<const f32x4*>(input + base0 + c * HW + q);
        *reinterpret_cast<f32x4*>(&lds[(c << 10) + q]) = v;
    }

    // ---- Weights for positions p0 = 2t, p1 = 2t+1 (overlap staging) ----
    const int p0 = 2 * t;
    const f32x2 d2 = *reinterpret_cast<const f32x2*>(disp + bh * W + p0);

    float x   = fminf(fmaxf((float)p0 + d2[0], 0.0f), (float)(W - 1));
    int   ix  = (int)x;                  // == floor(x) since x >= 0
    float x0f = (float)ix;
    const float wr0 = x - x0f;
    const float wl0 = fminf(x0f + 1.0f, (float)(W - 1)) - x;
    const int   a0  = min(ix, W - 2);

    x   = fminf(fmaxf((float)(p0 + 1) + d2[1], 0.0f), (float)(W - 1));
    ix  = (int)x;
    x0f = (float)ix;
    const float wr1 = x - x0f;
    const float wl1 = fminf(x0f + 1.0f, (float)(W - 1)) - x;
    const int   a1  = min(ix, W - 2);

    __syncthreads();

    // ---- Gather from LDS, dwordx2 nontemporal stores ----
#pragma unroll
    for (int ch = 0; ch < CPB; ++ch) {
        const float* __restrict__ row = &lds[ch << 10];
        f32x2 o;
        o[0] = wl0 * row[a0] + wr0 * row[a0 + 1];
        o[1] = wl1 * row[a1] + wr1 * row[a1 + 1];
        __builtin_nontemporal_store(
            o, reinterpret_cast<f32x2*>(out + base0 + ch * HW + p0));
    }
}

extern "C" void kernel_launch(void* const* d_in, const int* in_sizes, int n_in,
                              void* d_out, int out_size, void* d_ws, size_t ws_size,
                              hipStream_t stream) {
    const float* input = (const float*)d_in[0];
    const float* disp  = (const float*)d_in[1];
    float* out = (float*)d_out;

    warp_lds_x2<<<NBLK, THREADS, 0, stream>>>(input, disp, out);
}